// Round 8
// baseline (164.433 us; speedup 1.0000x reference)
//
#include <hip/hip_runtime.h>

static constexpr int C  = 512;
static constexpr int P  = 4096;    // H*W

typedef _Float16 half8  __attribute__((ext_vector_type(8)));
typedef _Float16 half2v __attribute__((ext_vector_type(2)));
typedef float    f32x4  __attribute__((ext_vector_type(4)));
typedef float    f32x16 __attribute__((ext_vector_type(16)));

__device__ __forceinline__ int refl(int q) { return q < 0 ? 1 : (q > 63 ? 62 : q); }

__device__ __forceinline__ void g2l16(const void* g, const void* l) {
    __builtin_amdgcn_global_load_lds((const __attribute__((address_space(1))) unsigned int*)g,
                                     (__attribute__((address_space(3))) unsigned int*)l, 16, 0, 0);
}

// ---------------- transpose fp32 [c][p] -> fp16 [p][c]; per-cblk style sq-norm partials ----------------
__global__ __launch_bounds__(256) void k_prep(const float* __restrict__ content, const float* __restrict__ style,
                                              _Float16* __restrict__ Ah, _Float16* __restrict__ Bh,
                                              float* __restrict__ sqn_part) {
    __shared__ float T[64][65];
    __shared__ float R4[4][64];
    const int p0 = (blockIdx.x & 63) * 64, c0 = (blockIdx.x >> 6) * 64;
    const int pl = threadIdx.x & 63, cq = threadIdx.x >> 6;   // read role
    const int pv = threadIdx.x >> 3;                           // write role: p row 0..31 (+32)
    const int cv = (threadIdx.x & 7) * 8;                      // write role: c base

    // content
    #pragma unroll
    for (int r = 0; r < 16; ++r)
        T[cq + r * 4][pl] = content[(size_t)(c0 + cq + r * 4) * P + p0 + pl];
    __syncthreads();
    #pragma unroll
    for (int r = 0; r < 2; ++r) {
        int pl2 = pv + r * 32;
        half8 v;
        #pragma unroll
        for (int u = 0; u < 8; ++u) v[u] = (_Float16)T[cv + u][pl2];
        *(half8*)(Ah + (size_t)(p0 + pl2) * C + c0 + cv) = v;
    }
    __syncthreads();

    // style
    float sq = 0.f;
    #pragma unroll
    for (int r = 0; r < 16; ++r) {
        float v = style[(size_t)(c0 + cq + r * 4) * P + p0 + pl];
        T[cq + r * 4][pl] = v;
        sq += v * v;
    }
    R4[cq][pl] = sq;
    __syncthreads();
    if (cq == 0)
        sqn_part[(size_t)(blockIdx.x >> 6) * P + p0 + pl] = R4[0][pl] + R4[1][pl] + R4[2][pl] + R4[3][pl];
    #pragma unroll
    for (int r = 0; r < 2; ++r) {
        int pl2 = pv + r * 32;
        half8 v;
        #pragma unroll
        for (int u = 0; u < 8; ++u) v[u] = (_Float16)T[cv + u][pl2];
        *(half8*)(Bh + (size_t)(p0 + pl2) * C + c0 + cv) = v;
    }
}

// ---------------- 3x3 reflect box-sum of (sum of 8 partials) -> 1/patch_norm; block 0: mask sum ----------------
__global__ void k_pnorm(const float* __restrict__ sqn_part, const float* __restrict__ mask,
                        float* __restrict__ inv_sn, float* __restrict__ msum) {
    __shared__ float sqs[6][64];
    const int b = blockIdx.x;
    for (int e = threadIdx.x; e < 384; e += 256) {
        int rr = e >> 6, jw = e & 63;
        int gr = refl(b * 4 - 1 + rr);
        float s = 0.f;
        #pragma unroll
        for (int k = 0; k < 8; ++k) s += sqn_part[(size_t)k * P + gr * 64 + jw];
        sqs[rr][jw] = s;
    }
    __syncthreads();

    int p = b * 256 + threadIdx.x;
    int li = (threadIdx.x >> 6) + 1;
    int j = p & 63;
    float s2 = 0.f;
    #pragma unroll
    for (int dh = -1; dh <= 1; ++dh) {
        #pragma unroll
        for (int dw = -1; dw <= 1; ++dw)
            s2 += sqs[li + dh][refl(j + dw)];
    }
    inv_sn[p] = 1.0f / sqrtf(s2);

    if (b == 0) {
        __shared__ float red[256];
        float s = 0.f;
        for (int e = threadIdx.x; e < P; e += 256) s += mask[e];
        red[threadIdx.x] = s;
        __syncthreads();
        for (int t = 128; t > 0; t >>= 1) {
            if (threadIdx.x < t) red[threadIdx.x] += red[threadIdx.x + t];
            __syncthreads();
        }
        if (threadIdx.x == 0) msum[0] = red[0];
    }
}

// ---------------- D0 GEMM (32x32x16 MFMA) + fused w-diagonal 3-sum epilogue -> E ----------------
// r8: 32x32x16 halves MFMA issue count at same ds_read count; C/D mapping per m74/m101:
// col=lane&31, row=(reg&3)+8*(reg>>2)+4*(lane>>5). A/B frag: row=lane&31, k-octet=(lane>>5)*8.
__global__ __launch_bounds__(256) void k_gemm16(const _Float16* __restrict__ Ah,
                                                const _Float16* __restrict__ Bh,
                                                _Float16* __restrict__ Eo) {
    __shared__ _Float16 SH[16640];             // max(As+Bs = 16384, tile 128*130 = 16640)
    _Float16* As = SH;
    _Float16* Bs = SH + 8192;
    const int tid = threadIdx.x;
    const int wave = tid >> 6, lane = tid & 63;
    const int wr = wave >> 1, wc = wave & 1;
    const int l31 = lane & 31, hl = lane >> 5;
    const int i0 = blockIdx.y * 128, j0 = blockIdx.x * 128;

    int mloc[4], goff[4];
    #pragma unroll
    for (int c2 = 0; c2 < 4; ++c2) {
        int m = wave * 32 + c2 * 8 + (lane >> 3);
        mloc[c2] = m;
        goff[c2] = ((lane & 7) ^ (m & 7)) * 8;
    }

    int aoff[2][4], boff[2][4];
    #pragma unroll
    for (int mi = 0; mi < 2; ++mi) {
        int m = wr * 64 + mi * 32 + l31;
        int n = wc * 64 + mi * 32 + l31;
        #pragma unroll
        for (int ks = 0; ks < 4; ++ks) {
            aoff[mi][ks] = m * 64 + ((2 * ks + hl) ^ (m & 7)) * 8;
            boff[mi][ks] = n * 64 + ((2 * ks + hl) ^ (n & 7)) * 8;
        }
    }

    f32x16 acc[2][2] = {};

    for (int kk = 0; kk < C; kk += 64) {
        __syncthreads();
        #pragma unroll
        for (int c2 = 0; c2 < 4; ++c2) {
            g2l16(Ah + (size_t)(i0 + mloc[c2]) * C + kk + goff[c2], As + (wave * 32 + c2 * 8) * 64);
            g2l16(Bh + (size_t)(j0 + mloc[c2]) * C + kk + goff[c2], Bs + (wave * 32 + c2 * 8) * 64);
        }
        __syncthreads();
        half8 af[2][4], bf[2][4];
        #pragma unroll
        for (int mi = 0; mi < 2; ++mi)
            #pragma unroll
            for (int ks = 0; ks < 4; ++ks) {
                af[mi][ks] = *(const half8*)(As + aoff[mi][ks]);
                bf[mi][ks] = *(const half8*)(Bs + boff[mi][ks]);
            }
        #pragma unroll
        for (int ks = 0; ks < 4; ++ks)
            #pragma unroll
            for (int mi = 0; mi < 2; ++mi)
                #pragma unroll
                for (int ni = 0; ni < 2; ++ni)
                    acc[mi][ni] = __builtin_amdgcn_mfma_f32_32x32x16_f16(af[mi][ks], bf[ni][ks], acc[mi][ni], 0, 0, 0);
    }

    // epilogue: acc -> LDS fp16 tile (stride 130), then E = w-diagonal 3-sum -> global
    __syncthreads();
    #pragma unroll
    for (int mi = 0; mi < 2; ++mi)
        #pragma unroll
        for (int ni = 0; ni < 2; ++ni)
            #pragma unroll
            for (int r = 0; r < 16; ++r) {
                int row = wr * 64 + mi * 32 + (r & 3) + 8 * (r >> 2) + 4 * hl;
                int col = wc * 64 + ni * 32 + l31;
                SH[row * 130 + col] = (_Float16)acc[mi][ni][r];
            }
    __syncthreads();

    const int er  = tid >> 1;
    const int ec0 = (tid & 1) << 6;
    const int aw = er & 63;
    const int rm = (er & 64) | (aw == 0 ? 1 : aw - 1);
    const int rp = (er & 64) | (aw == 63 ? 62 : aw + 1);
    _Float16* outRow = Eo + (size_t)(i0 + er) * P + j0 + ec0;
    #pragma unroll
    for (int cc = 0; cc < 64; cc += 8) {
        half8 ev;
        #pragma unroll
        for (int u = 0; u < 8; ++u) {
            int c = ec0 + cc + u;
            int cw = c & 63;
            int cm = (c & 64) | (cw == 0 ? 1 : cw - 1);
            int cp = (c & 64) | (cw == 63 ? 62 : cw + 1);
            ev[u] = (_Float16)((float)SH[rm * 130 + cm] + (float)SH[er * 130 + c] + (float)SH[rp * 130 + cp]);
        }
        *(half8*)(outRow + cc) = ev;
    }
}

// ---------------- h-diagonal 3-sum + normalize + argmax (unchanged from r6) ----------------
__global__ __launch_bounds__(256) void k_argmax(const _Float16* __restrict__ E,
                                                const float* __restrict__ inv_sn,
                                                int* __restrict__ idxOut) {
    const int i = blockIdx.x;
    const int ih = i >> 6, iw = i & 63;
    const int wave = threadIdx.x >> 6, l = threadIdx.x & 63, l15 = l & 15;
    size_t rb0 = (size_t)(refl(ih - 1) * 64 + iw) * P;
    size_t rb1 = (size_t)(ih * 64 + iw) * P;
    size_t rb2 = (size_t)(refl(ih + 1) * 64 + iw) * P;

    float best = -1e30f;
    int bidx = 0;
    #pragma unroll
    for (int s = 0; s < 4; ++s) {
        const int j0 = (wave * 4 + s) * 256 + l * 4;
        const int jh = j0 >> 6, jw0 = l15 * 4;
        const int cb0 = ((jh == 0) ? 1 : jh - 1) * 64 + jw0;
        const int cb1 = jh * 64 + jw0;
        const int cb2 = ((jh == 63) ? 62 : jh + 1) * 64 + jw0;
        uint2 u0 = *(const uint2*)(E + rb0 + cb0);
        uint2 u1 = *(const uint2*)(E + rb1 + cb1);
        uint2 u2 = *(const uint2*)(E + rb2 + cb2);
        half2v a0 = __builtin_bit_cast(half2v, u0.x), a1 = __builtin_bit_cast(half2v, u0.y);
        half2v b0 = __builtin_bit_cast(half2v, u1.x), b1 = __builtin_bit_cast(half2v, u1.y);
        half2v c0 = __builtin_bit_cast(half2v, u2.x), c1 = __builtin_bit_cast(half2v, u2.y);
        float f0 = (float)a0[0] + (float)b0[0] + (float)c0[0];
        float f1 = (float)a0[1] + (float)b0[1] + (float)c0[1];
        float f2 = (float)a1[0] + (float)b1[0] + (float)c1[0];
        float f3 = (float)a1[1] + (float)b1[1] + (float)c1[1];
        const float4 is = *(const float4*)(inv_sn + j0);
        float v0 = f0 * is.x, v1 = f1 * is.y, v2 = f2 * is.z, v3 = f3 * is.w;
        if (v0 > best) { best = v0; bidx = j0; }
        if (v1 > best) { best = v1; bidx = j0 + 1; }
        if (v2 > best) { best = v2; bidx = j0 + 2; }
        if (v3 > best) { best = v3; bidx = j0 + 3; }
    }

    __shared__ float bv[256];
    __shared__ int   bi[256];
    bv[threadIdx.x] = best;
    bi[threadIdx.x] = bidx;
    __syncthreads();
    for (int t = 128; t > 0; t >>= 1) {
        if (threadIdx.x < t) {
            float ov = bv[threadIdx.x + t];
            int   oi = bi[threadIdx.x + t];
            if (ov > bv[threadIdx.x] || (ov == bv[threadIdx.x] && oi < bi[threadIdx.x])) {
                bv[threadIdx.x] = ov;
                bi[threadIdx.x] = oi;
            }
        }
        __syncthreads();
    }
    if (threadIdx.x == 0) idxOut[i] = bi[0];
}

// ---------------- build masked fp16 matrices; fc gathered as coalesced Bh ROWS + LDS transpose ----------------
// r8: fc[c][p] = Bh[idx[p]][c]*m[p]; each gather is a contiguous 1KB row (64 lanes x half8)
// vs 2M scattered 4B column loads. fg folded in (flat, independent indexing).
__global__ __launch_bounds__(256) void k_build(const _Float16* __restrict__ Bh,
                                               const float* __restrict__ input,
                                               const float* __restrict__ mask,
                                               const int* __restrict__ idx,
                                               _Float16* __restrict__ fc, _Float16* __restrict__ fg) {
    __shared__ _Float16 G[32][520];            // stride 520: 260 dw, %32=4 -> banks spread
    __shared__ float mk[32];
    const int p0 = blockIdx.x * 32;            // 128 blocks
    const int wave = threadIdx.x >> 6, lane = threadIdx.x & 63;

    // fg: input*mask, 64 flat elements per thread
    {
        int e0 = (blockIdx.x * 256 + threadIdx.x) * 64;
        #pragma unroll
        for (int v = 0; v < 8; ++v) {
            int e = e0 + v * 8;
            int pp = e & (P - 1);
            half8 vg;
            #pragma unroll
            for (int u = 0; u < 8; ++u)
                vg[u] = (_Float16)(input[e + u] * mask[pp + u]);
            *(half8*)(fg + e) = vg;
        }
    }

    if (threadIdx.x < 32) mk[threadIdx.x] = mask[p0 + threadIdx.x];

    // gather 32 style rows (fp16, from Bh[p][c]) into LDS — fully coalesced
    #pragma unroll
    for (int r = 0; r < 8; ++r) {
        int pp = wave * 8 + r;
        int row = idx[p0 + pp];                // wave-uniform
        *(half8*)(&G[pp][lane * 8]) = *(const half8*)(Bh + (size_t)row * C + lane * 8);
    }
    __syncthreads();

    // transpose + mask: thread handles channel c and c+256; writes one full 64B line per c
    #pragma unroll
    for (int h = 0; h < 2; ++h) {
        int c = h * 256 + threadIdx.x;
        half8 o[4];
        #pragma unroll
        for (int q = 0; q < 4; ++q)
            #pragma unroll
            for (int u = 0; u < 8; ++u) {
                int p = q * 8 + u;
                o[q][u] = (_Float16)((float)G[p][c] * mk[p]);
            }
        _Float16* dst = fc + (size_t)c * P + p0;
        *(half8*)(dst)      = o[0];
        *(half8*)(dst + 8)  = o[1];
        *(half8*)(dst + 16) = o[2];
        *(half8*)(dst + 24) = o[3];
    }
}

// ---------------- gram diff partials, lower-triangle tiles only (G, T symmetric) ----------------
__device__ __constant__ int TBX[10] = {0, 0, 1, 0, 1, 2, 0, 1, 2, 3};
__device__ __constant__ int TBY[10] = {0, 1, 1, 2, 2, 2, 3, 3, 3, 3};

__global__ __launch_bounds__(256) void k_gram(const _Float16* __restrict__ fg,
                                              const _Float16* __restrict__ fc,
                                              float* __restrict__ part) {
    const int t = blockIdx.x, z = blockIdx.z;
    const int p0 = z * 256;
    const int wave = threadIdx.x >> 6, lane = threadIdx.x & 63;
    const int wr = wave >> 1, wc = wave & 1, quad = lane >> 4, l15 = lane & 15;
    const int a0 = TBY[t] * 128 + wr * 64, b0 = TBX[t] * 128 + wc * 64;

    f32x4 accg[4][4] = {};
    f32x4 accc[4][4] = {};
    for (int ks = 0; ks < 256; ks += 32) {
        int kbase = p0 + ks + quad * 8;
        half8 af[4], bf[4];
        #pragma unroll
        for (int mi = 0; mi < 4; ++mi) af[mi] = *(const half8*)(fg + (size_t)(a0 + mi * 16 + l15) * P + kbase);
        #pragma unroll
        for (int ni = 0; ni < 4; ++ni) bf[ni] = *(const half8*)(fg + (size_t)(b0 + ni * 16 + l15) * P + kbase);
        #pragma unroll
        for (int mi = 0; mi < 4; ++mi)
            #pragma unroll
            for (int ni = 0; ni < 4; ++ni)
                accg[mi][ni] = __builtin_amdgcn_mfma_f32_16x16x32_f16(af[mi], bf[ni], accg[mi][ni], 0, 0, 0);
        #pragma unroll
        for (int mi = 0; mi < 4; ++mi) af[mi] = *(const half8*)(fc + (size_t)(a0 + mi * 16 + l15) * P + kbase);
        #pragma unroll
        for (int ni = 0; ni < 4; ++ni) bf[ni] = *(const half8*)(fc + (size_t)(b0 + ni * 16 + l15) * P + kbase);
        #pragma unroll
        for (int mi = 0; mi < 4; ++mi)
            #pragma unroll
            for (int ni = 0; ni < 4; ++ni)
                accc[mi][ni] = __builtin_amdgcn_mfma_f32_16x16x32_f16(af[mi], bf[ni], accc[mi][ni], 0, 0, 0);
    }
    float* dst = part + (size_t)(z * 10 + t) * 16384;
    #pragma unroll
    for (int mi = 0; mi < 4; ++mi)
        #pragma unroll
        for (int ni = 0; ni < 4; ++ni)
            #pragma unroll
            for (int r = 0; r < 4; ++r)
                dst[(wr * 64 + mi * 16 + quad * 4 + r) * 128 + wc * 64 + ni * 16 + l15]
                    = accg[mi][ni][r] - accc[mi][ni][r];
}

// ---------------- loss partials: w[t]*(sum_z part)^2, plain store ----------------
__global__ void k_loss(const float* __restrict__ part, float* __restrict__ lsum) {
    int e = blockIdx.x * 256 + threadIdx.x;
    int t = e >> 14, loc = e & 16383;
    float d = 0.f;
    #pragma unroll
    for (int z = 0; z < 16; ++z) d += part[(size_t)(z * 10 + t) * 16384 + loc];
    float w = (TBX[t] == TBY[t]) ? 1.0f : 2.0f;
    __shared__ float red[256];
    red[threadIdx.x] = d * d * w;
    __syncthreads();
    for (int s = 128; s > 0; s >>= 1) {
        if (threadIdx.x < s) red[threadIdx.x] += red[threadIdx.x + s];
        __syncthreads();
    }
    if (threadIdx.x == 0) lsum[blockIdx.x] = red[0];
}

__global__ void k_final(const float* __restrict__ lsum, const float* __restrict__ msum,
                        float* __restrict__ out) {
    __shared__ float red[256];
    float s = 0.f;
    for (int e = threadIdx.x; e < 640; e += 256) s += lsum[e];
    red[threadIdx.x] = s;
    __syncthreads();
    for (int t = 128; t > 0; t >>= 1) {
        if (threadIdx.x < t) red[threadIdx.x] += red[threadIdx.x + t];
        __syncthreads();
    }
    if (threadIdx.x == 0) {
        float m = msum[0];
        out[0] = red[0] * 100.0f / (m * m * 262144.0f);
    }
}

extern "C" void kernel_launch(void* const* d_in, const int* in_sizes, int n_in,
                              void* d_out, int out_size, void* d_ws, size_t ws_size,
                              hipStream_t stream) {
    (void)in_sizes; (void)n_in; (void)out_size; (void)ws_size;
    const float* content = (const float*)d_in[0];
    const float* style   = (const float*)d_in[1];
    const float* input   = (const float*)d_in[2];
    const float* mask    = (const float*)d_in[3];

    char* ws = (char*)d_ws;
    _Float16* Eb   = (_Float16*)ws;                        // 32 MB (dead after k_argmax)
    float*    part = (float*)ws;                           // 10.5 MB (overlays Eb)
    _Float16* Ah   = (_Float16*)(ws + (32u << 20));        // 4 MB
    _Float16* Bh   = (_Float16*)(ws + (36u << 20));        // 4 MB
    _Float16* fg_h = (_Float16*)(ws + (40u << 20));        // 4 MB
    _Float16* fc_h = (_Float16*)(ws + (44u << 20));        // 4 MB
    float*    small = (float*)(ws + (48u << 20));
    float* sqn_part = small;               // 8*4096
    float* inv_sn   = small + 32768;       // 4096
    float* msum     = small + 36864;
    float* lsum     = small + 36992;       // 640
    int*   idx      = (int*)(small + 37888);
    float* out = (float*)d_out;

    k_prep  <<<512, 256, 0, stream>>>(content, style, Ah, Bh, sqn_part);
    k_pnorm <<<16, 256, 0, stream>>>(sqn_part, mask, inv_sn, msum);
    k_gemm16<<<dim3(32, 32), 256, 0, stream>>>(Ah, Bh, Eb);
    k_argmax<<<4096, 256, 0, stream>>>(Eb, inv_sn, idx);
    k_build <<<128, 256, 0, stream>>>(Bh, input, mask, idx, fc_h, fg_h);
    k_gram  <<<dim3(10, 1, 16), 256, 0, stream>>>(fg_h, fc_h, part);
    k_loss  <<<640, 256, 0, stream>>>(part, lsum);
    k_final <<<1, 256, 0, stream>>>(lsum, msum, out);
}

// Round 9
// 158.765 us; speedup vs baseline: 1.0357x; 1.0357x over previous
//
#include <hip/hip_runtime.h>

static constexpr int C  = 512;
static constexpr int P  = 4096;    // H*W

typedef _Float16 half8  __attribute__((ext_vector_type(8)));
typedef _Float16 half2v __attribute__((ext_vector_type(2)));
typedef float    f32x4  __attribute__((ext_vector_type(4)));

__device__ __forceinline__ int refl(int q) { return q < 0 ? 1 : (q > 63 ? 62 : q); }

__device__ __forceinline__ void g2l16(const void* g, const void* l) {
    __builtin_amdgcn_global_load_lds((const __attribute__((address_space(1))) unsigned int*)g,
                                     (__attribute__((address_space(3))) unsigned int*)l, 16, 0, 0);
}

// ---------------- transpose fp32 [c][p] -> fp16 [p][c]; per-cblk style sq-norm partials ----------------
__global__ __launch_bounds__(256) void k_prep(const float* __restrict__ content, const float* __restrict__ style,
                                              _Float16* __restrict__ Ah, _Float16* __restrict__ Bh,
                                              float* __restrict__ sqn_part) {
    __shared__ float T[64][65];
    __shared__ float R4[4][64];
    const int p0 = (blockIdx.x & 63) * 64, c0 = (blockIdx.x >> 6) * 64;
    const int pl = threadIdx.x & 63, cq = threadIdx.x >> 6;   // read role
    const int pv = threadIdx.x >> 3;                           // write role: p row 0..31 (+32)
    const int cv = (threadIdx.x & 7) * 8;                      // write role: c base

    // content
    #pragma unroll
    for (int r = 0; r < 16; ++r)
        T[cq + r * 4][pl] = content[(size_t)(c0 + cq + r * 4) * P + p0 + pl];
    __syncthreads();
    #pragma unroll
    for (int r = 0; r < 2; ++r) {
        int pl2 = pv + r * 32;
        half8 v;
        #pragma unroll
        for (int u = 0; u < 8; ++u) v[u] = (_Float16)T[cv + u][pl2];
        *(half8*)(Ah + (size_t)(p0 + pl2) * C + c0 + cv) = v;
    }
    __syncthreads();

    // style
    float sq = 0.f;
    #pragma unroll
    for (int r = 0; r < 16; ++r) {
        float v = style[(size_t)(c0 + cq + r * 4) * P + p0 + pl];
        T[cq + r * 4][pl] = v;
        sq += v * v;
    }
    R4[cq][pl] = sq;
    __syncthreads();
    if (cq == 0)
        sqn_part[(size_t)(blockIdx.x >> 6) * P + p0 + pl] = R4[0][pl] + R4[1][pl] + R4[2][pl] + R4[3][pl];
    #pragma unroll
    for (int r = 0; r < 2; ++r) {
        int pl2 = pv + r * 32;
        half8 v;
        #pragma unroll
        for (int u = 0; u < 8; ++u) v[u] = (_Float16)T[cv + u][pl2];
        *(half8*)(Bh + (size_t)(p0 + pl2) * C + c0 + cv) = v;
    }
}

// ---------------- 3x3 reflect box-sum of (sum of 8 partials) -> 1/patch_norm; block 0: mask sum ----------------
__global__ void k_pnorm(const float* __restrict__ sqn_part, const float* __restrict__ mask,
                        float* __restrict__ inv_sn, float* __restrict__ msum) {
    __shared__ float sqs[6][64];
    const int b = blockIdx.x;
    for (int e = threadIdx.x; e < 384; e += 256) {
        int rr = e >> 6, jw = e & 63;
        int gr = refl(b * 4 - 1 + rr);
        float s = 0.f;
        #pragma unroll
        for (int k = 0; k < 8; ++k) s += sqn_part[(size_t)k * P + gr * 64 + jw];
        sqs[rr][jw] = s;
    }
    __syncthreads();

    int p = b * 256 + threadIdx.x;
    int li = (threadIdx.x >> 6) + 1;
    int j = p & 63;
    float s2 = 0.f;
    #pragma unroll
    for (int dh = -1; dh <= 1; ++dh) {
        #pragma unroll
        for (int dw = -1; dw <= 1; ++dw)
            s2 += sqs[li + dh][refl(j + dw)];
    }
    inv_sn[p] = 1.0f / sqrtf(s2);

    if (b == 0) {
        __shared__ float red[256];
        float s = 0.f;
        for (int e = threadIdx.x; e < P; e += 256) s += mask[e];
        red[threadIdx.x] = s;
        __syncthreads();
        for (int t = 128; t > 0; t >>= 1) {
            if (threadIdx.x < t) red[threadIdx.x] += red[threadIdx.x + t];
            __syncthreads();
        }
        if (threadIdx.x == 0) msum[0] = red[0];
    }
}

// ---------------- D0 GEMM (16x16x32 MFMA, r7-verified) + fused w-diagonal 3-sum epilogue -> E ----------------
// r9: reverted from 32x32x16 (r8 regressed: only 4 independent acc chains -> MFMA dep stalls,
// plus per-reg epilogue address math). 16 independent 16x16 accs is the right ILP for this tile.
__global__ __launch_bounds__(256) void k_gemm16(const _Float16* __restrict__ Ah,
                                                const _Float16* __restrict__ Bh,
                                                _Float16* __restrict__ Eo) {
    __shared__ _Float16 SH[16640];             // max(As+Bs = 16384, tile 128*130 = 16640)
    _Float16* As = SH;
    _Float16* Bs = SH + 8192;
    const int tid = threadIdx.x;
    const int wave = tid >> 6, lane = tid & 63;
    const int wr = wave >> 1, wc = wave & 1;
    const int quad = lane >> 4, l15 = lane & 15;
    const int i0 = blockIdx.y * 128, j0 = blockIdx.x * 128;

    int mloc[4], goff[4];
    #pragma unroll
    for (int c2 = 0; c2 < 4; ++c2) {
        int m = wave * 32 + c2 * 8 + (lane >> 3);
        mloc[c2] = m;
        goff[c2] = ((lane & 7) ^ (m & 7)) * 8;
    }

    int aoff[4][2], boff[4][2];
    #pragma unroll
    for (int mi = 0; mi < 4; ++mi) {
        int m = wr * 64 + mi * 16 + l15;
        int n = wc * 64 + mi * 16 + l15;
        #pragma unroll
        for (int kh = 0; kh < 2; ++kh) {
            aoff[mi][kh] = m * 64 + ((quad + kh * 4) ^ (m & 7)) * 8;
            boff[mi][kh] = n * 64 + ((quad + kh * 4) ^ (n & 7)) * 8;
        }
    }

    f32x4 acc[4][4] = {};

    for (int kk = 0; kk < C; kk += 64) {
        __syncthreads();
        #pragma unroll
        for (int c2 = 0; c2 < 4; ++c2) {
            g2l16(Ah + (size_t)(i0 + mloc[c2]) * C + kk + goff[c2], As + (wave * 32 + c2 * 8) * 64);
            g2l16(Bh + (size_t)(j0 + mloc[c2]) * C + kk + goff[c2], Bs + (wave * 32 + c2 * 8) * 64);
        }
        __syncthreads();
        half8 af[2][4], bf[2][4];
        #pragma unroll
        for (int kh = 0; kh < 2; ++kh)
            #pragma unroll
            for (int mi = 0; mi < 4; ++mi) {
                af[kh][mi] = *(const half8*)(As + aoff[mi][kh]);
                bf[kh][mi] = *(const half8*)(Bs + boff[mi][kh]);
            }
        #pragma unroll
        for (int kh = 0; kh < 2; ++kh)
            #pragma unroll
            for (int mi = 0; mi < 4; ++mi)
                #pragma unroll
                for (int ni = 0; ni < 4; ++ni)
                    acc[mi][ni] = __builtin_amdgcn_mfma_f32_16x16x32_f16(af[kh][mi], bf[kh][ni], acc[mi][ni], 0, 0, 0);
    }

    // epilogue: acc -> LDS fp16 tile (stride 130), then E = w-diagonal 3-sum -> global
    __syncthreads();
    #pragma unroll
    for (int mi = 0; mi < 4; ++mi) {
        int row = wr * 64 + mi * 16 + quad * 4;
        #pragma unroll
        for (int ni = 0; ni < 4; ++ni) {
            int col = wc * 64 + ni * 16 + l15;
            #pragma unroll
            for (int r = 0; r < 4; ++r)
                SH[(row + r) * 130 + col] = (_Float16)acc[mi][ni][r];
        }
    }
    __syncthreads();

    const int er  = tid >> 1;
    const int ec0 = (tid & 1) << 6;
    const int aw = er & 63;
    const int rm = (er & 64) | (aw == 0 ? 1 : aw - 1);
    const int rp = (er & 64) | (aw == 63 ? 62 : aw + 1);
    _Float16* outRow = Eo + (size_t)(i0 + er) * P + j0 + ec0;
    #pragma unroll
    for (int cc = 0; cc < 64; cc += 8) {
        half8 ev;
        #pragma unroll
        for (int u = 0; u < 8; ++u) {
            int c = ec0 + cc + u;
            int cw = c & 63;
            int cm = (c & 64) | (cw == 0 ? 1 : cw - 1);
            int cp = (c & 64) | (cw == 63 ? 62 : cw + 1);
            ev[u] = (_Float16)((float)SH[rm * 130 + cm] + (float)SH[er * 130 + c] + (float)SH[rp * 130 + cp]);
        }
        *(half8*)(outRow + cc) = ev;
    }
}

// ---------------- h-diagonal 3-sum + normalize + argmax (r6-verified) ----------------
__global__ __launch_bounds__(256) void k_argmax(const _Float16* __restrict__ E,
                                                const float* __restrict__ inv_sn,
                                                int* __restrict__ idxOut) {
    const int i = blockIdx.x;
    const int ih = i >> 6, iw = i & 63;
    const int wave = threadIdx.x >> 6, l = threadIdx.x & 63, l15 = l & 15;
    size_t rb0 = (size_t)(refl(ih - 1) * 64 + iw) * P;
    size_t rb1 = (size_t)(ih * 64 + iw) * P;
    size_t rb2 = (size_t)(refl(ih + 1) * 64 + iw) * P;

    float best = -1e30f;
    int bidx = 0;
    #pragma unroll
    for (int s = 0; s < 4; ++s) {
        const int j0 = (wave * 4 + s) * 256 + l * 4;
        const int jh = j0 >> 6, jw0 = l15 * 4;
        const int cb0 = ((jh == 0) ? 1 : jh - 1) * 64 + jw0;
        const int cb1 = jh * 64 + jw0;
        const int cb2 = ((jh == 63) ? 62 : jh + 1) * 64 + jw0;
        uint2 u0 = *(const uint2*)(E + rb0 + cb0);
        uint2 u1 = *(const uint2*)(E + rb1 + cb1);
        uint2 u2 = *(const uint2*)(E + rb2 + cb2);
        half2v a0 = __builtin_bit_cast(half2v, u0.x), a1 = __builtin_bit_cast(half2v, u0.y);
        half2v b0 = __builtin_bit_cast(half2v, u1.x), b1 = __builtin_bit_cast(half2v, u1.y);
        half2v c0 = __builtin_bit_cast(half2v, u2.x), c1 = __builtin_bit_cast(half2v, u2.y);
        float f0 = (float)a0[0] + (float)b0[0] + (float)c0[0];
        float f1 = (float)a0[1] + (float)b0[1] + (float)c0[1];
        float f2 = (float)a1[0] + (float)b1[0] + (float)c1[0];
        float f3 = (float)a1[1] + (float)b1[1] + (float)c1[1];
        const float4 is = *(const float4*)(inv_sn + j0);
        float v0 = f0 * is.x, v1 = f1 * is.y, v2 = f2 * is.z, v3 = f3 * is.w;
        if (v0 > best) { best = v0; bidx = j0; }
        if (v1 > best) { best = v1; bidx = j0 + 1; }
        if (v2 > best) { best = v2; bidx = j0 + 2; }
        if (v3 > best) { best = v3; bidx = j0 + 3; }
    }

    __shared__ float bv[256];
    __shared__ int   bi[256];
    bv[threadIdx.x] = best;
    bi[threadIdx.x] = bidx;
    __syncthreads();
    for (int t = 128; t > 0; t >>= 1) {
        if (threadIdx.x < t) {
            float ov = bv[threadIdx.x + t];
            int   oi = bi[threadIdx.x + t];
            if (ov > bv[threadIdx.x] || (ov == bv[threadIdx.x] && oi < bi[threadIdx.x])) {
                bv[threadIdx.x] = ov;
                bi[threadIdx.x] = oi;
            }
        }
        __syncthreads();
    }
    if (threadIdx.x == 0) idxOut[i] = bi[0];
}

// ---------------- build masked fp16 matrices; fc gathered as coalesced Bh ROWS + LDS transpose (r8) ----------------
__global__ __launch_bounds__(256) void k_build(const _Float16* __restrict__ Bh,
                                               const float* __restrict__ input,
                                               const float* __restrict__ mask,
                                               const int* __restrict__ idx,
                                               _Float16* __restrict__ fc, _Float16* __restrict__ fg) {
    __shared__ _Float16 G[32][520];            // stride 520: 260 dw, %32=4 -> banks spread
    __shared__ float mk[32];
    const int p0 = blockIdx.x * 32;            // 128 blocks
    const int wave = threadIdx.x >> 6, lane = threadIdx.x & 63;

    // fg: input*mask, 64 flat elements per thread
    {
        int e0 = (blockIdx.x * 256 + threadIdx.x) * 64;
        #pragma unroll
        for (int v = 0; v < 8; ++v) {
            int e = e0 + v * 8;
            int pp = e & (P - 1);
            half8 vg;
            #pragma unroll
            for (int u = 0; u < 8; ++u)
                vg[u] = (_Float16)(input[e + u] * mask[pp + u]);
            *(half8*)(fg + e) = vg;
        }
    }

    if (threadIdx.x < 32) mk[threadIdx.x] = mask[p0 + threadIdx.x];

    // gather 32 style rows (fp16, from Bh[p][c]) into LDS — fully coalesced
    #pragma unroll
    for (int r = 0; r < 8; ++r) {
        int pp = wave * 8 + r;
        int row = idx[p0 + pp];                // wave-uniform
        *(half8*)(&G[pp][lane * 8]) = *(const half8*)(Bh + (size_t)row * C + lane * 8);
    }
    __syncthreads();

    // transpose + mask: thread handles channel c and c+256; writes one full 64B line per c
    #pragma unroll
    for (int h = 0; h < 2; ++h) {
        int c = h * 256 + threadIdx.x;
        half8 o[4];
        #pragma unroll
        for (int q = 0; q < 4; ++q)
            #pragma unroll
            for (int u = 0; u < 8; ++u) {
                int p = q * 8 + u;
                o[q][u] = (_Float16)((float)G[p][c] * mk[p]);
            }
        _Float16* dst = fc + (size_t)c * P + p0;
        *(half8*)(dst)      = o[0];
        *(half8*)(dst + 8)  = o[1];
        *(half8*)(dst + 16) = o[2];
        *(half8*)(dst + 24) = o[3];
    }
}

// ---------------- gram diff partials, lower-triangle tiles only (G, T symmetric) ----------------
__device__ __constant__ int TBX[10] = {0, 0, 1, 0, 1, 2, 0, 1, 2, 3};
__device__ __constant__ int TBY[10] = {0, 1, 1, 2, 2, 2, 3, 3, 3, 3};

__global__ __launch_bounds__(256) void k_gram(const _Float16* __restrict__ fg,
                                              const _Float16* __restrict__ fc,
                                              float* __restrict__ part) {
    const int t = blockIdx.x, z = blockIdx.z;
    const int p0 = z * 256;
    const int wave = threadIdx.x >> 6, lane = threadIdx.x & 63;
    const int wr = wave >> 1, wc = wave & 1, quad = lane >> 4, l15 = lane & 15;
    const int a0 = TBY[t] * 128 + wr * 64, b0 = TBX[t] * 128 + wc * 64;

    f32x4 accg[4][4] = {};
    f32x4 accc[4][4] = {};
    for (int ks = 0; ks < 256; ks += 32) {
        int kbase = p0 + ks + quad * 8;
        half8 af[4], bf[4];
        #pragma unroll
        for (int mi = 0; mi < 4; ++mi) af[mi] = *(const half8*)(fg + (size_t)(a0 + mi * 16 + l15) * P + kbase);
        #pragma unroll
        for (int ni = 0; ni < 4; ++ni) bf[ni] = *(const half8*)(fg + (size_t)(b0 + ni * 16 + l15) * P + kbase);
        #pragma unroll
        for (int mi = 0; mi < 4; ++mi)
            #pragma unroll
            for (int ni = 0; ni < 4; ++ni)
                accg[mi][ni] = __builtin_amdgcn_mfma_f32_16x16x32_f16(af[mi], bf[ni], accg[mi][ni], 0, 0, 0);
        #pragma unroll
        for (int mi = 0; mi < 4; ++mi) af[mi] = *(const half8*)(fc + (size_t)(a0 + mi * 16 + l15) * P + kbase);
        #pragma unroll
        for (int ni = 0; ni < 4; ++ni) bf[ni] = *(const half8*)(fc + (size_t)(b0 + ni * 16 + l15) * P + kbase);
        #pragma unroll
        for (int mi = 0; mi < 4; ++mi)
            #pragma unroll
            for (int ni = 0; ni < 4; ++ni)
                accc[mi][ni] = __builtin_amdgcn_mfma_f32_16x16x32_f16(af[mi], bf[ni], accc[mi][ni], 0, 0, 0);
    }
    float* dst = part + (size_t)(z * 10 + t) * 16384;
    #pragma unroll
    for (int mi = 0; mi < 4; ++mi)
        #pragma unroll
        for (int ni = 0; ni < 4; ++ni)
            #pragma unroll
            for (int r = 0; r < 4; ++r)
                dst[(wr * 64 + mi * 16 + quad * 4 + r) * 128 + wc * 64 + ni * 16 + l15]
                    = accg[mi][ni][r] - accc[mi][ni][r];
}

// ---------------- loss partials: w[t]*(sum_z part)^2, plain store ----------------
__global__ void k_loss(const float* __restrict__ part, float* __restrict__ lsum) {
    int e = blockIdx.x * 256 + threadIdx.x;
    int t = e >> 14, loc = e & 16383;
    float d = 0.f;
    #pragma unroll
    for (int z = 0; z < 16; ++z) d += part[(size_t)(z * 10 + t) * 16384 + loc];
    float w = (TBX[t] == TBY[t]) ? 1.0f : 2.0f;
    __shared__ float red[256];
    red[threadIdx.x] = d * d * w;
    __syncthreads();
    for (int s = 128; s > 0; s >>= 1) {
        if (threadIdx.x < s) red[threadIdx.x] += red[threadIdx.x + s];
        __syncthreads();
    }
    if (threadIdx.x == 0) lsum[blockIdx.x] = red[0];
}

__global__ void k_final(const float* __restrict__ lsum, const float* __restrict__ msum,
                        float* __restrict__ out) {
    __shared__ float red[256];
    float s = 0.f;
    for (int e = threadIdx.x; e < 640; e += 256) s += lsum[e];
    red[threadIdx.x] = s;
    __syncthreads();
    for (int t = 128; t > 0; t >>= 1) {
        if (threadIdx.x < t) red[threadIdx.x] += red[threadIdx.x + t];
        __syncthreads();
    }
    if (threadIdx.x == 0) {
        float m = msum[0];
        out[0] = red[0] * 100.0f / (m * m * 262144.0f);
    }
}

extern "C" void kernel_launch(void* const* d_in, const int* in_sizes, int n_in,
                              void* d_out, int out_size, void* d_ws, size_t ws_size,
                              hipStream_t stream) {
    (void)in_sizes; (void)n_in; (void)out_size; (void)ws_size;
    const float* content = (const float*)d_in[0];
    const float* style   = (const float*)d_in[1];
    const float* input   = (const float*)d_in[2];
    const float* mask    = (const float*)d_in[3];

    char* ws = (char*)d_ws;
    _Float16* Eb   = (_Float16*)ws;                        // 32 MB (dead after k_argmax)
    float*    part = (float*)ws;                           // 10.5 MB (overlays Eb)
    _Float16* Ah   = (_Float16*)(ws + (32u << 20));        // 4 MB
    _Float16* Bh   = (_Float16*)(ws + (36u << 20));        // 4 MB
    _Float16* fg_h = (_Float16*)(ws + (40u << 20));        // 4 MB
    _Float16* fc_h = (_Float16*)(ws + (44u << 20));        // 4 MB
    float*    small = (float*)(ws + (48u << 20));
    float* sqn_part = small;               // 8*4096
    float* inv_sn   = small + 32768;       // 4096
    float* msum     = small + 36864;
    float* lsum     = small + 36992;       // 640
    int*   idx      = (int*)(small + 37888);
    float* out = (float*)d_out;

    k_prep  <<<512, 256, 0, stream>>>(content, style, Ah, Bh, sqn_part);
    k_pnorm <<<16, 256, 0, stream>>>(sqn_part, mask, inv_sn, msum);
    k_gemm16<<<dim3(32, 32), 256, 0, stream>>>(Ah, Bh, Eb);
    k_argmax<<<4096, 256, 0, stream>>>(Eb, inv_sn, idx);
    k_build <<<128, 256, 0, stream>>>(Bh, input, mask, idx, fc_h, fg_h);
    k_gram  <<<dim3(10, 1, 16), 256, 0, stream>>>(fg_h, fc_h, part);
    k_loss  <<<640, 256, 0, stream>>>(part, lsum);
    k_final <<<1, 256, 0, stream>>>(lsum, msum, out);
}

// Round 10
// 149.927 us; speedup vs baseline: 1.0967x; 1.0589x over previous
//
#include <hip/hip_runtime.h>

static constexpr int C  = 512;
static constexpr int P  = 4096;    // H*W

typedef _Float16 half8  __attribute__((ext_vector_type(8)));
typedef _Float16 half2v __attribute__((ext_vector_type(2)));
typedef float    f32x4  __attribute__((ext_vector_type(4)));

__device__ __forceinline__ int refl(int q) { return q < 0 ? 1 : (q > 63 ? 62 : q); }

__device__ __forceinline__ void g2l16(const void* g, const void* l) {
    __builtin_amdgcn_global_load_lds((const __attribute__((address_space(1))) unsigned int*)g,
                                     (__attribute__((address_space(3))) unsigned int*)l, 16, 0, 0);
}

// ---------------- transpose fp32 [c][p] -> fp16 [p][c]; per-cblk style sq-norm partials ----------------
__global__ __launch_bounds__(256) void k_prep(const float* __restrict__ content, const float* __restrict__ style,
                                              _Float16* __restrict__ Ah, _Float16* __restrict__ Bh,
                                              float* __restrict__ sqn_part) {
    __shared__ float T[64][65];
    __shared__ float R4[4][64];
    const int p0 = (blockIdx.x & 63) * 64, c0 = (blockIdx.x >> 6) * 64;
    const int pl = threadIdx.x & 63, cq = threadIdx.x >> 6;   // read role
    const int pv = threadIdx.x >> 3;                           // write role: p row 0..31 (+32)
    const int cv = (threadIdx.x & 7) * 8;                      // write role: c base

    // content
    #pragma unroll
    for (int r = 0; r < 16; ++r)
        T[cq + r * 4][pl] = content[(size_t)(c0 + cq + r * 4) * P + p0 + pl];
    __syncthreads();
    #pragma unroll
    for (int r = 0; r < 2; ++r) {
        int pl2 = pv + r * 32;
        half8 v;
        #pragma unroll
        for (int u = 0; u < 8; ++u) v[u] = (_Float16)T[cv + u][pl2];
        *(half8*)(Ah + (size_t)(p0 + pl2) * C + c0 + cv) = v;
    }
    __syncthreads();

    // style
    float sq = 0.f;
    #pragma unroll
    for (int r = 0; r < 16; ++r) {
        float v = style[(size_t)(c0 + cq + r * 4) * P + p0 + pl];
        T[cq + r * 4][pl] = v;
        sq += v * v;
    }
    R4[cq][pl] = sq;
    __syncthreads();
    if (cq == 0)
        sqn_part[(size_t)(blockIdx.x >> 6) * P + p0 + pl] = R4[0][pl] + R4[1][pl] + R4[2][pl] + R4[3][pl];
    #pragma unroll
    for (int r = 0; r < 2; ++r) {
        int pl2 = pv + r * 32;
        half8 v;
        #pragma unroll
        for (int u = 0; u < 8; ++u) v[u] = (_Float16)T[cv + u][pl2];
        *(half8*)(Bh + (size_t)(p0 + pl2) * C + c0 + cv) = v;
    }
}

// ---------------- D0 GEMM (16x16x32, r7-verified) + fused w-diagonal 3-sum epilogue -> E ----------------
// r10: pnorm+msum folded into blocks (y==0, x<16) as a preamble — work hidden under gemm,
// saves a launch. inv_sn/msum consumed only by LATER kernels (kernel-boundary visibility, no fence).
__global__ __launch_bounds__(256) void k_gemm16(const _Float16* __restrict__ Ah,
                                                const _Float16* __restrict__ Bh,
                                                _Float16* __restrict__ Eo,
                                                const float* __restrict__ sqn_part,
                                                const float* __restrict__ mask,
                                                float* __restrict__ inv_sn,
                                                float* __restrict__ msum) {
    __shared__ _Float16 SH[16640];             // max(As+Bs = 16384, tile 128*130 = 16640)
    _Float16* As = SH;
    _Float16* Bs = SH + 8192;
    const int tid = threadIdx.x;

    // ---- pnorm preamble (16 blocks) ----
    if (blockIdx.y == 0 && blockIdx.x < 16) {
        float* sqs = (float*)SH;               // 6*64 floats, aliases staging LDS (resynced below)
        const int b = blockIdx.x;
        for (int e = tid; e < 384; e += 256) {
            int rr = e >> 6, jw = e & 63;
            int gr = refl(b * 4 - 1 + rr);
            float s = 0.f;
            #pragma unroll
            for (int k = 0; k < 8; ++k) s += sqn_part[(size_t)k * P + gr * 64 + jw];
            sqs[rr * 64 + jw] = s;
        }
        __syncthreads();
        {
            int p = b * 256 + tid;
            int li = (tid >> 6) + 1;
            int j = p & 63;
            float s2 = 0.f;
            #pragma unroll
            for (int dh = -1; dh <= 1; ++dh)
                #pragma unroll
                for (int dw = -1; dw <= 1; ++dw)
                    s2 += sqs[(li + dh) * 64 + refl(j + dw)];
            inv_sn[p] = 1.0f / sqrtf(s2);
        }
        if (b == 0) {
            __syncthreads();
            float* red = (float*)SH;
            float s = 0.f;
            for (int e = tid; e < P; e += 256) s += mask[e];
            red[tid] = s;
            __syncthreads();
            for (int t = 128; t > 0; t >>= 1) {
                if (tid < t) red[tid] += red[tid + t];
                __syncthreads();
            }
            if (tid == 0) msum[0] = red[0];
        }
    }

    const int wave = tid >> 6, lane = tid & 63;
    const int wr = wave >> 1, wc = wave & 1;
    const int quad = lane >> 4, l15 = lane & 15;
    const int i0 = blockIdx.y * 128, j0 = blockIdx.x * 128;

    int mloc[4], goff[4];
    #pragma unroll
    for (int c2 = 0; c2 < 4; ++c2) {
        int m = wave * 32 + c2 * 8 + (lane >> 3);
        mloc[c2] = m;
        goff[c2] = ((lane & 7) ^ (m & 7)) * 8;
    }

    int aoff[4][2], boff[4][2];
    #pragma unroll
    for (int mi = 0; mi < 4; ++mi) {
        int m = wr * 64 + mi * 16 + l15;
        int n = wc * 64 + mi * 16 + l15;
        #pragma unroll
        for (int kh = 0; kh < 2; ++kh) {
            aoff[mi][kh] = m * 64 + ((quad + kh * 4) ^ (m & 7)) * 8;
            boff[mi][kh] = n * 64 + ((quad + kh * 4) ^ (n & 7)) * 8;
        }
    }

    f32x4 acc[4][4] = {};

    for (int kk = 0; kk < C; kk += 64) {
        __syncthreads();
        #pragma unroll
        for (int c2 = 0; c2 < 4; ++c2) {
            g2l16(Ah + (size_t)(i0 + mloc[c2]) * C + kk + goff[c2], As + (wave * 32 + c2 * 8) * 64);
            g2l16(Bh + (size_t)(j0 + mloc[c2]) * C + kk + goff[c2], Bs + (wave * 32 + c2 * 8) * 64);
        }
        __syncthreads();
        half8 af[2][4], bf[2][4];
        #pragma unroll
        for (int kh = 0; kh < 2; ++kh)
            #pragma unroll
            for (int mi = 0; mi < 4; ++mi) {
                af[kh][mi] = *(const half8*)(As + aoff[mi][kh]);
                bf[kh][mi] = *(const half8*)(Bs + boff[mi][kh]);
            }
        #pragma unroll
        for (int kh = 0; kh < 2; ++kh)
            #pragma unroll
            for (int mi = 0; mi < 4; ++mi)
                #pragma unroll
                for (int ni = 0; ni < 4; ++ni)
                    acc[mi][ni] = __builtin_amdgcn_mfma_f32_16x16x32_f16(af[kh][mi], bf[kh][ni], acc[mi][ni], 0, 0, 0);
    }

    // epilogue: acc -> LDS fp16 tile (stride 130), then E = w-diagonal 3-sum -> global
    __syncthreads();
    #pragma unroll
    for (int mi = 0; mi < 4; ++mi) {
        int row = wr * 64 + mi * 16 + quad * 4;
        #pragma unroll
        for (int ni = 0; ni < 4; ++ni) {
            int col = wc * 64 + ni * 16 + l15;
            #pragma unroll
            for (int r = 0; r < 4; ++r)
                SH[(row + r) * 130 + col] = (_Float16)acc[mi][ni][r];
        }
    }
    __syncthreads();

    const int er  = tid >> 1;
    const int ec0 = (tid & 1) << 6;
    const int aw = er & 63;
    const int rm = (er & 64) | (aw == 0 ? 1 : aw - 1);
    const int rp = (er & 64) | (aw == 63 ? 62 : aw + 1);
    _Float16* outRow = Eo + (size_t)(i0 + er) * P + j0 + ec0;
    #pragma unroll
    for (int cc = 0; cc < 64; cc += 8) {
        half8 ev;
        #pragma unroll
        for (int u = 0; u < 8; ++u) {
            int c = ec0 + cc + u;
            int cw = c & 63;
            int cm = (c & 64) | (cw == 0 ? 1 : cw - 1);
            int cp = (c & 64) | (cw == 63 ? 62 : cw + 1);
            ev[u] = (_Float16)((float)SH[rm * 130 + cm] + (float)SH[er * 130 + c] + (float)SH[rp * 130 + cp]);
        }
        *(half8*)(outRow + cc) = ev;
    }
}

// ---------------- h-diagonal 3-sum + normalize + argmax (r6-verified) ----------------
__global__ __launch_bounds__(256) void k_argmax(const _Float16* __restrict__ E,
                                                const float* __restrict__ inv_sn,
                                                int* __restrict__ idxOut) {
    const int i = blockIdx.x;
    const int ih = i >> 6, iw = i & 63;
    const int wave = threadIdx.x >> 6, l = threadIdx.x & 63, l15 = l & 15;
    size_t rb0 = (size_t)(refl(ih - 1) * 64 + iw) * P;
    size_t rb1 = (size_t)(ih * 64 + iw) * P;
    size_t rb2 = (size_t)(refl(ih + 1) * 64 + iw) * P;

    float best = -1e30f;
    int bidx = 0;
    #pragma unroll
    for (int s = 0; s < 4; ++s) {
        const int j0 = (wave * 4 + s) * 256 + l * 4;
        const int jh = j0 >> 6, jw0 = l15 * 4;
        const int cb0 = ((jh == 0) ? 1 : jh - 1) * 64 + jw0;
        const int cb1 = jh * 64 + jw0;
        const int cb2 = ((jh == 63) ? 62 : jh + 1) * 64 + jw0;
        uint2 u0 = *(const uint2*)(E + rb0 + cb0);
        uint2 u1 = *(const uint2*)(E + rb1 + cb1);
        uint2 u2 = *(const uint2*)(E + rb2 + cb2);
        half2v a0 = __builtin_bit_cast(half2v, u0.x), a1 = __builtin_bit_cast(half2v, u0.y);
        half2v b0 = __builtin_bit_cast(half2v, u1.x), b1 = __builtin_bit_cast(half2v, u1.y);
        half2v c0 = __builtin_bit_cast(half2v, u2.x), c1 = __builtin_bit_cast(half2v, u2.y);
        float f0 = (float)a0[0] + (float)b0[0] + (float)c0[0];
        float f1 = (float)a0[1] + (float)b0[1] + (float)c0[1];
        float f2 = (float)a1[0] + (float)b1[0] + (float)c1[0];
        float f3 = (float)a1[1] + (float)b1[1] + (float)c1[1];
        const float4 is = *(const float4*)(inv_sn + j0);
        float v0 = f0 * is.x, v1 = f1 * is.y, v2 = f2 * is.z, v3 = f3 * is.w;
        if (v0 > best) { best = v0; bidx = j0; }
        if (v1 > best) { best = v1; bidx = j0 + 1; }
        if (v2 > best) { best = v2; bidx = j0 + 2; }
        if (v3 > best) { best = v3; bidx = j0 + 3; }
    }

    __shared__ float bv[256];
    __shared__ int   bi[256];
    bv[threadIdx.x] = best;
    bi[threadIdx.x] = bidx;
    __syncthreads();
    for (int t = 128; t > 0; t >>= 1) {
        if (threadIdx.x < t) {
            float ov = bv[threadIdx.x + t];
            int   oi = bi[threadIdx.x + t];
            if (ov > bv[threadIdx.x] || (ov == bv[threadIdx.x] && oi < bi[threadIdx.x])) {
                bv[threadIdx.x] = ov;
                bi[threadIdx.x] = oi;
            }
        }
        __syncthreads();
    }
    if (threadIdx.x == 0) idxOut[i] = bi[0];
}

// ---------------- build masked fp16 matrices; coalesced row-gather, 256 blocks (r10: occupancy fix) ----------------
__global__ __launch_bounds__(256) void k_build(const _Float16* __restrict__ Bh,
                                               const float* __restrict__ input,
                                               const float* __restrict__ mask,
                                               const int* __restrict__ idx,
                                               _Float16* __restrict__ fc, _Float16* __restrict__ fg) {
    __shared__ _Float16 G[16][520];
    __shared__ float mk[16];
    const int p0 = blockIdx.x * 16;            // 256 blocks
    const int wave = threadIdx.x >> 6, lane = threadIdx.x & 63;

    // fg: input*mask, 32 flat elements per thread
    {
        int e0 = (blockIdx.x * 256 + threadIdx.x) * 32;
        #pragma unroll
        for (int v = 0; v < 4; ++v) {
            int e = e0 + v * 8;
            int pp = e & (P - 1);
            half8 vg;
            #pragma unroll
            for (int u = 0; u < 8; ++u)
                vg[u] = (_Float16)(input[e + u] * mask[pp + u]);
            *(half8*)(fg + e) = vg;
        }
    }

    if (threadIdx.x < 16) mk[threadIdx.x] = mask[p0 + threadIdx.x];

    // gather 16 style rows (fp16, from Bh[p][c]) into LDS — fully coalesced
    #pragma unroll
    for (int r = 0; r < 4; ++r) {
        int pp = wave * 4 + r;
        int row = idx[p0 + pp];                // wave-uniform
        *(half8*)(&G[pp][lane * 8]) = *(const half8*)(Bh + (size_t)row * C + lane * 8);
    }
    __syncthreads();

    // transpose + mask: thread handles channel c and c+256; 32B store per c
    #pragma unroll
    for (int h = 0; h < 2; ++h) {
        int c = h * 256 + threadIdx.x;
        half8 o[2];
        #pragma unroll
        for (int q = 0; q < 2; ++q)
            #pragma unroll
            for (int u = 0; u < 8; ++u) {
                int p = q * 8 + u;
                o[q][u] = (_Float16)((float)G[p][c] * mk[p]);
            }
        _Float16* dst = fc + (size_t)c * P + p0;
        *(half8*)(dst)     = o[0];
        *(half8*)(dst + 8) = o[1];
    }
}

// ---------------- gram diff partials, lower-triangle tiles only (G, T symmetric) ----------------
__device__ __constant__ int TBX[10] = {0, 0, 1, 0, 1, 2, 0, 1, 2, 3};
__device__ __constant__ int TBY[10] = {0, 1, 1, 2, 2, 2, 3, 3, 3, 3};

__global__ __launch_bounds__(256) void k_gram(const _Float16* __restrict__ fg,
                                              const _Float16* __restrict__ fc,
                                              float* __restrict__ part) {
    const int t = blockIdx.x, z = blockIdx.z;
    const int p0 = z * 256;
    const int wave = threadIdx.x >> 6, lane = threadIdx.x & 63;
    const int wr = wave >> 1, wc = wave & 1, quad = lane >> 4, l15 = lane & 15;
    const int a0 = TBY[t] * 128 + wr * 64, b0 = TBX[t] * 128 + wc * 64;

    f32x4 accg[4][4] = {};
    f32x4 accc[4][4] = {};
    for (int ks = 0; ks < 256; ks += 32) {
        int kbase = p0 + ks + quad * 8;
        half8 af[4], bf[4];
        #pragma unroll
        for (int mi = 0; mi < 4; ++mi) af[mi] = *(const half8*)(fg + (size_t)(a0 + mi * 16 + l15) * P + kbase);
        #pragma unroll
        for (int ni = 0; ni < 4; ++ni) bf[ni] = *(const half8*)(fg + (size_t)(b0 + ni * 16 + l15) * P + kbase);
        #pragma unroll
        for (int mi = 0; mi < 4; ++mi)
            #pragma unroll
            for (int ni = 0; ni < 4; ++ni)
                accg[mi][ni] = __builtin_amdgcn_mfma_f32_16x16x32_f16(af[mi], bf[ni], accg[mi][ni], 0, 0, 0);
        #pragma unroll
        for (int mi = 0; mi < 4; ++mi) af[mi] = *(const half8*)(fc + (size_t)(a0 + mi * 16 + l15) * P + kbase);
        #pragma unroll
        for (int ni = 0; ni < 4; ++ni) bf[ni] = *(const half8*)(fc + (size_t)(b0 + ni * 16 + l15) * P + kbase);
        #pragma unroll
        for (int mi = 0; mi < 4; ++mi)
            #pragma unroll
            for (int ni = 0; ni < 4; ++ni)
                accc[mi][ni] = __builtin_amdgcn_mfma_f32_16x16x32_f16(af[mi], bf[ni], accc[mi][ni], 0, 0, 0);
    }
    float* dst = part + (size_t)(z * 10 + t) * 16384;
    #pragma unroll
    for (int mi = 0; mi < 4; ++mi)
        #pragma unroll
        for (int ni = 0; ni < 4; ++ni)
            #pragma unroll
            for (int r = 0; r < 4; ++r)
                dst[(wr * 64 + mi * 16 + quad * 4 + r) * 128 + wc * 64 + ni * 16 + l15]
                    = accg[mi][ni][r] - accc[mi][ni][r];
}

// ---------------- loss partials: w[t]*(sum_z part)^2, plain store ----------------
__global__ void k_loss(const float* __restrict__ part, float* __restrict__ lsum) {
    int e = blockIdx.x * 256 + threadIdx.x;
    int t = e >> 14, loc = e & 16383;
    float d = 0.f;
    #pragma unroll
    for (int z = 0; z < 16; ++z) d += part[(size_t)(z * 10 + t) * 16384 + loc];
    float w = (TBX[t] == TBY[t]) ? 1.0f : 2.0f;
    __shared__ float red[256];
    red[threadIdx.x] = d * d * w;
    __syncthreads();
    for (int s = 128; s > 0; s >>= 1) {
        if (threadIdx.x < s) red[threadIdx.x] += red[threadIdx.x + s];
        __syncthreads();
    }
    if (threadIdx.x == 0) lsum[blockIdx.x] = red[0];
}

__global__ void k_final(const float* __restrict__ lsum, const float* __restrict__ msum,
                        float* __restrict__ out) {
    __shared__ float red[256];
    float s = 0.f;
    for (int e = threadIdx.x; e < 640; e += 256) s += lsum[e];
    red[threadIdx.x] = s;
    __syncthreads();
    for (int t = 128; t > 0; t >>= 1) {
        if (threadIdx.x < t) red[threadIdx.x] += red[threadIdx.x + t];
        __syncthreads();
    }
    if (threadIdx.x == 0) {
        float m = msum[0];
        out[0] = red[0] * 100.0f / (m * m * 262144.0f);
    }
}

extern "C" void kernel_launch(void* const* d_in, const int* in_sizes, int n_in,
                              void* d_out, int out_size, void* d_ws, size_t ws_size,
                              hipStream_t stream) {
    (void)in_sizes; (void)n_in; (void)out_size; (void)ws_size;
    const float* content = (const float*)d_in[0];
    const float* style   = (const float*)d_in[1];
    const float* input   = (const float*)d_in[2];
    const float* mask    = (const float*)d_in[3];

    char* ws = (char*)d_ws;
    _Float16* Eb   = (_Float16*)ws;                        // 32 MB (dead after k_argmax)
    float*    part = (float*)ws;                           // 10.5 MB (overlays Eb)
    _Float16* Ah   = (_Float16*)(ws + (32u << 20));        // 4 MB
    _Float16* Bh   = (_Float16*)(ws + (36u << 20));        // 4 MB
    _Float16* fg_h = (_Float16*)(ws + (40u << 20));        // 4 MB
    _Float16* fc_h = (_Float16*)(ws + (44u << 20));        // 4 MB
    float*    small = (float*)(ws + (48u << 20));
    float* sqn_part = small;               // 8*4096
    float* inv_sn   = small + 32768;       // 4096
    float* msum     = small + 36864;
    float* lsum     = small + 36992;       // 640
    int*   idx      = (int*)(small + 37888);
    float* out = (float*)d_out;

    k_prep  <<<512, 256, 0, stream>>>(content, style, Ah, Bh, sqn_part);
    k_gemm16<<<dim3(32, 32), 256, 0, stream>>>(Ah, Bh, Eb, sqn_part, mask, inv_sn, msum);
    k_argmax<<<4096, 256, 0, stream>>>(Eb, inv_sn, idx);
    k_build <<<256, 256, 0, stream>>>(Bh, input, mask, idx, fc_h, fg_h);
    k_gram  <<<dim3(10, 1, 16), 256, 0, stream>>>(fg_h, fc_h, part);
    k_loss  <<<640, 256, 0, stream>>>(part, lsum);
    k_final <<<1, 256, 0, stream>>>(lsum, msum, out);
}